// Round 2
// baseline (478.163 us; speedup 1.0000x reference)
//
#include <hip/hip_runtime.h>
#include <hip/hip_bf16.h>

// DynamicConv1dTBC: T=2048 B=4 C=1024 H=16 K=15 PAD_L=14 (causal)
// out[t,b,h*64+r] = sum_k softmax_k(x[t,b,:]·Wlin[h*15+k,:]) * x[t+k-14,b,h*64+r]

#define T_DIM 2048
#define B_DIM 4
#define C_DIM 1024
#define H_DIM 16
#define K_TAPS 15
#define R_DIM 64
#define N_DIM (H_DIM * K_TAPS)   // 240
#define M_DIM (T_DIM * B_DIM)    // 8192

// ---------------- Kernel 1: GEMM (M=8192, K=1024, N=240) + fused softmax ----
// 64 rows/block, 256 threads. Thread = 4 rows x 15 cols (one head's taps)
// so the tap-softmax lives entirely in registers in the epilogue.
__global__ __launch_bounds__(256) void gemm_softmax_kernel(
    const float* __restrict__ x, const float* __restrict__ Wlin,
    float* __restrict__ wbuf)
{
    __shared__ float xs[64][17];    // +1 pad
    __shared__ float wl[240][17];

    const int tid = threadIdx.x;
    const int m0 = blockIdx.x * 64;
    const int row_base = (tid & 15) * 4;       // 0..60
    const int head = tid >> 4;                 // 0..15
    const int col_base = head * K_TAPS;        // 0..225

    float acc[4][K_TAPS];
    #pragma unroll
    for (int r = 0; r < 4; ++r)
        #pragma unroll
        for (int c = 0; c < K_TAPS; ++c) acc[r][c] = 0.f;

    for (int k0 = 0; k0 < C_DIM; k0 += 16) {
        // stage x tile 64x16 (4 elems/thread, 16-float segments)
        #pragma unroll
        for (int i = 0; i < 4; ++i) {
            int idx = tid + i * 256;           // 0..1023
            int rr = idx >> 4, cc = idx & 15;
            xs[rr][cc] = x[(size_t)(m0 + rr) * C_DIM + k0 + cc];
        }
        // stage Wlin tile 240x16 (15 elems/thread)
        for (int idx = tid; idx < N_DIM * 16; idx += 256) {
            int nn = idx >> 4, cc = idx & 15;
            wl[nn][cc] = Wlin[(size_t)nn * C_DIM + k0 + cc];
        }
        __syncthreads();
        #pragma unroll
        for (int kk = 0; kk < 16; ++kk) {
            float a[4], b[K_TAPS];
            #pragma unroll
            for (int r = 0; r < 4; ++r) a[r] = xs[row_base + r][kk];
            #pragma unroll
            for (int c = 0; c < K_TAPS; ++c) b[c] = wl[col_base + c][kk];
            #pragma unroll
            for (int r = 0; r < 4; ++r)
                #pragma unroll
                for (int c = 0; c < K_TAPS; ++c)
                    acc[r][c] += a[r] * b[c];
        }
        __syncthreads();
    }

    // epilogue: per-row softmax over the 15 taps, write w
    #pragma unroll
    for (int r = 0; r < 4; ++r) {
        float mx = acc[r][0];
        #pragma unroll
        for (int c = 1; c < K_TAPS; ++c) mx = fmaxf(mx, acc[r][c]);
        float s = 0.f;
        #pragma unroll
        for (int c = 0; c < K_TAPS; ++c) {
            acc[r][c] = __expf(acc[r][c] - mx);
            s += acc[r][c];
        }
        float inv = 1.f / s;
        int m = m0 + row_base + r;
        float* dst = wbuf + (size_t)m * N_DIM + col_base;
        #pragma unroll
        for (int c = 0; c < K_TAPS; ++c) dst[c] = acc[r][c] * inv;
    }
}

// ---------------- Kernel 2: depthwise causal conv along t --------------------
// grid = (T/64, B*H); block 256. Stage x[t0-14 .. t0+63, b, h*64 .. +63] in LDS.
__global__ __launch_bounds__(256) void conv_kernel(
    const float* __restrict__ x, const float* __restrict__ wbuf,
    float* __restrict__ out)
{
    __shared__ float xs[64 + K_TAPS - 1][R_DIM];   // 78 x 64 = 20 KB

    const int tid = threadIdx.x;
    const int t0 = blockIdx.x * 64;
    const int bh = blockIdx.y;
    const int b = bh >> 4;          // bh = b*16 + h
    const int h = bh & 15;
    const int cbase = h * R_DIM;

    for (int idx = tid; idx < (64 + K_TAPS - 1) * R_DIM; idx += 256) {
        int row = idx >> 6, r = idx & 63;
        int t = t0 - (K_TAPS - 1) + row;
        xs[row][r] = (t >= 0) ? x[((size_t)t * B_DIM + b) * C_DIM + cbase + r] : 0.f;
    }
    __syncthreads();

    const int r = tid & 63;
    const int tg = tid >> 6;        // 0..3
    for (int i = 0; i < 16; ++i) {
        int tl = tg * 16 + i;       // local t in [0,64)
        int t = t0 + tl;
        const float* wp = wbuf + ((size_t)t * B_DIM + b) * N_DIM + h * K_TAPS;
        float accv = 0.f;
        #pragma unroll
        for (int k = 0; k < K_TAPS; ++k)
            accv += wp[k] * xs[tl + k][r];      // xs row tl+k = x[t+k-14]
        out[((size_t)t * B_DIM + b) * C_DIM + cbase + r] = accv;
    }
}

extern "C" void kernel_launch(void* const* d_in, const int* in_sizes, int n_in,
                              void* d_out, int out_size, void* d_ws, size_t ws_size,
                              hipStream_t stream) {
    const float* x    = (const float*)d_in[0];   // (T,B,C) fp32
    const float* Wlin = (const float*)d_in[1];   // (240,1024) fp32
    float* out  = (float*)d_out;                 // (T,B,C) fp32
    float* wbuf = (float*)d_ws;                  // needs M*240*4 = 7.86 MB scratch

    gemm_softmax_kernel<<<M_DIM / 64, 256, 0, stream>>>(x, Wlin, wbuf);
    conv_kernel<<<dim3(T_DIM / 64, B_DIM * H_DIM), 256, 0, stream>>>(x, wbuf, out);
}

// Round 3
// 140.533 us; speedup vs baseline: 3.4025x; 3.4025x over previous
//
#include <hip/hip_runtime.h>
#include <hip/hip_bf16.h>

// DynamicConv1dTBC: T=2048 B=4 C=1024 H=16 K=15 PAD_L=14 (causal)
// out[t,b,h*64+r] = sum_k softmax_k(x[t,b,:]·Wlin[h*15+k,:]) * x[t+k-14,b,h*64+r]

#define T_DIM 2048
#define B_DIM 4
#define C_DIM 1024
#define H_DIM 16
#define K_TAPS 15
#define R_DIM 64
#define N_DIM (H_DIM * K_TAPS)   // 240
#define M_DIM (T_DIM * B_DIM)    // 8192

typedef __attribute__((ext_vector_type(8))) short bf16x8;
typedef __attribute__((ext_vector_type(4))) float f32x4;

// fp32 -> bf16 round-to-nearest-even (bit pattern as ushort)
__device__ __forceinline__ unsigned short f2bf(float f) {
    union { float f; unsigned u; } v; v.f = f;
    return (unsigned short)((v.u + 0x7FFFu + ((v.u >> 16) & 1u)) >> 16);
}

// ---------------- Kernel 0: convert Wlin (240x1024 fp32) -> bf16 ------------
__global__ __launch_bounds__(256) void convert_w(
    const float* __restrict__ W, unsigned short* __restrict__ Wbf)
{
    int i = (blockIdx.x * 256 + threadIdx.x) * 4;   // grid covers 245760 elems
    float4 v = *reinterpret_cast<const float4*>(W + i);
    ushort4 o;
    o.x = f2bf(v.x); o.y = f2bf(v.y); o.z = f2bf(v.z); o.w = f2bf(v.w);
    *reinterpret_cast<ushort4*>(Wbf + i) = o;
}

// ---------------- Kernel 1: MFMA GEMM (M=8192,K=1024,N=240) + softmax -------
// 1 wave per block, grid = 512. Wave owns 16 rows x all 240 cols.
// A-frag: lane l holds x[m0 + (l&15)][k0 + (l>>4)*8 .. +7] (fp32->bf16 in-reg)
// B-frag: lane l holds Wbf[nt*16 + (l&15)][k0 + (l>>4)*8 .. +7] (16B load)
// D: lane l, reg j -> row (l>>4)*4+j, col l&15  (verified m89/m91 layout)
__global__ __launch_bounds__(64) void gemm_softmax_mfma(
    const float* __restrict__ x, const unsigned short* __restrict__ Wbf,
    float* __restrict__ wbuf)
{
    __shared__ float sm[16 * N_DIM];   // 16 rows x 240 logits, 15 KB

    const int l   = threadIdx.x;
    const int m0  = blockIdx.x * 16;
    const int row = l & 15;
    const int kg  = l >> 4;            // 0..3

    f32x4 acc[15];
    #pragma unroll
    for (int nt = 0; nt < 15; ++nt) acc[nt] = (f32x4){0.f, 0.f, 0.f, 0.f};

    const float* xp = x + (size_t)(m0 + row) * C_DIM + kg * 8;
    const unsigned short* wp = Wbf + (size_t)row * C_DIM + kg * 8;

    #pragma unroll 2
    for (int ks = 0; ks < 32; ++ks) {
        const int k = ks * 32;
        // A fragment: 8 consecutive fp32 -> bf16
        float4 a0 = *reinterpret_cast<const float4*>(xp + k);
        float4 a1 = *reinterpret_cast<const float4*>(xp + k + 4);
        bf16x8 af;
        af[0] = (short)f2bf(a0.x); af[1] = (short)f2bf(a0.y);
        af[2] = (short)f2bf(a0.z); af[3] = (short)f2bf(a0.w);
        af[4] = (short)f2bf(a1.x); af[5] = (short)f2bf(a1.y);
        af[6] = (short)f2bf(a1.z); af[7] = (short)f2bf(a1.w);
        // B fragments: 15 x 16B bf16 loads (L2-resident Wbf)
        bf16x8 bfr[15];
        #pragma unroll
        for (int nt = 0; nt < 15; ++nt)
            bfr[nt] = *reinterpret_cast<const bf16x8*>(wp + (size_t)nt * 16 * C_DIM + k);
        #pragma unroll
        for (int nt = 0; nt < 15; ++nt)
            acc[nt] = __builtin_amdgcn_mfma_f32_16x16x32_bf16(af, bfr[nt], acc[nt], 0, 0, 0);
    }

    // scatter logits to LDS: D row = kg*4+j, col = nt*16 + row
    #pragma unroll
    for (int nt = 0; nt < 15; ++nt)
        #pragma unroll
        for (int j = 0; j < 4; ++j)
            sm[(kg * 4 + j) * N_DIM + nt * 16 + row] = acc[nt][j];
    __syncthreads();

    // softmax over 15 taps: each lane handles 4 (row, head) pairs
    #pragma unroll
    for (int p = 0; p < 4; ++p) {
        const int idx = l * 4 + p;       // 0..255 covers 16 rows x 16 heads
        const int r = idx >> 4;
        const int h = idx & 15;
        const float* s = sm + r * N_DIM + h * K_TAPS;
        float mx = s[0];
        #pragma unroll
        for (int kk = 1; kk < K_TAPS; ++kk) mx = fmaxf(mx, s[kk]);
        float e[K_TAPS], sum = 0.f;
        #pragma unroll
        for (int kk = 0; kk < K_TAPS; ++kk) {
            e[kk] = __expf(s[kk] - mx);
            sum += e[kk];
        }
        const float inv = 1.f / sum;
        float* dst = wbuf + (size_t)(m0 + r) * N_DIM + h * K_TAPS;
        #pragma unroll
        for (int kk = 0; kk < K_TAPS; ++kk) dst[kk] = e[kk] * inv;
    }
}

// ---------------- Kernel 2: depthwise causal conv along t --------------------
// grid = (T/64, B*H); block 256. Stage x[t0-14 .. t0+63, b, h*64 .. +63] in LDS.
__global__ __launch_bounds__(256) void conv_kernel(
    const float* __restrict__ x, const float* __restrict__ wbuf,
    float* __restrict__ out)
{
    __shared__ float xs[64 + K_TAPS - 1][R_DIM];   // 78 x 64 = 20 KB

    const int tid = threadIdx.x;
    const int t0 = blockIdx.x * 64;
    const int bh = blockIdx.y;
    const int b = bh >> 4;          // bh = b*16 + h
    const int h = bh & 15;
    const int cbase = h * R_DIM;

    for (int idx = tid; idx < (64 + K_TAPS - 1) * R_DIM; idx += 256) {
        int rrow = idx >> 6, r = idx & 63;
        int t = t0 - (K_TAPS - 1) + rrow;
        xs[rrow][r] = (t >= 0) ? x[((size_t)t * B_DIM + b) * C_DIM + cbase + r] : 0.f;
    }
    __syncthreads();

    const int r = tid & 63;
    const int tg = tid >> 6;        // 0..3
    for (int i = 0; i < 16; ++i) {
        int tl = tg * 16 + i;       // local t in [0,64)
        int t = t0 + tl;
        const float* wp = wbuf + ((size_t)t * B_DIM + b) * N_DIM + h * K_TAPS;
        float accv = 0.f;
        #pragma unroll
        for (int k = 0; k < K_TAPS; ++k)
            accv += wp[k] * xs[tl + k][r];      // xs row tl+k = x[t+k-14]
        out[((size_t)t * B_DIM + b) * C_DIM + cbase + r] = accv;
    }
}

extern "C" void kernel_launch(void* const* d_in, const int* in_sizes, int n_in,
                              void* d_out, int out_size, void* d_ws, size_t ws_size,
                              hipStream_t stream) {
    const float* x    = (const float*)d_in[0];   // (T,B,C) fp32
    const float* Wlin = (const float*)d_in[1];   // (240,1024) fp32
    float* out  = (float*)d_out;                 // (T,B,C) fp32

    // ws layout: [wbuf fp32 8192*240 = 7.86 MB][Wbf bf16 240*1024 = 0.49 MB]
    float* wbuf = (float*)d_ws;
    unsigned short* Wbf = (unsigned short*)((char*)d_ws + (size_t)M_DIM * N_DIM * sizeof(float));

    convert_w<<<(N_DIM * C_DIM) / (256 * 4), 256, 0, stream>>>(Wlin, Wbf);
    gemm_softmax_mfma<<<M_DIM / 16, 64, 0, stream>>>(x, Wbf, wbuf);
    conv_kernel<<<dim3(T_DIM / 64, B_DIM * H_DIM), 256, 0, stream>>>(x, wbuf, out);
}

// Round 4
// 127.880 us; speedup vs baseline: 3.7392x; 1.0989x over previous
//
#include <hip/hip_runtime.h>
#include <hip/hip_bf16.h>

// DynamicConv1dTBC: T=2048 B=4 C=1024 H=16 K=15 PAD_L=14 (causal)
// out[t,b,h*64+r] = sum_k softmax_k(x[t,b,:]·Wlin[h*15+k,:]) * x[t+k-14,b,h*64+r]

#define T_DIM 2048
#define B_DIM 4
#define C_DIM 1024
#define H_DIM 16
#define K_TAPS 15
#define R_DIM 64
#define N_DIM (H_DIM * K_TAPS)   // 240
#define M_DIM (T_DIM * B_DIM)    // 8192
#define SM_STRIDE 244            // pad: 4*244 % 32 == 16 -> kg groups 2-way (free)

typedef __attribute__((ext_vector_type(8))) short bf16x8;
typedef __attribute__((ext_vector_type(4))) float f32x4;

// fp32 -> bf16 round-to-nearest-even (bit pattern as ushort)
__device__ __forceinline__ unsigned short f2bf(float f) {
    union { float f; unsigned u; } v; v.f = f;
    return (unsigned short)((v.u + 0x7FFFu + ((v.u >> 16) & 1u)) >> 16);
}

// ---------------- Kernel 0: convert Wlin (240x1024 fp32) -> bf16 ------------
__global__ __launch_bounds__(256) void convert_w(
    const float* __restrict__ W, unsigned short* __restrict__ Wbf)
{
    int i = (blockIdx.x * 256 + threadIdx.x) * 4;   // grid covers 245760 elems
    float4 v = *reinterpret_cast<const float4*>(W + i);
    ushort4 o;
    o.x = f2bf(v.x); o.y = f2bf(v.y); o.z = f2bf(v.z); o.w = f2bf(v.w);
    *reinterpret_cast<ushort4*>(Wbf + i) = o;
}

// ---------------- Kernel 1: MFMA GEMM (M=8192,K=1024,N=240) + softmax -------
// Block = 256 threads = 4 waves, split-K: wave w handles k in [w*256,(w+1)*256).
// Each wave: same 16 rows x 240 cols, 8 K-steps of 32, partials to LDS,
// then 256 threads reduce 4 partials + softmax (thread = one (row,head) pair).
// Fragment layout identical to the R3-verified kernel.
__global__ __launch_bounds__(256) void gemm_softmax_mfma(
    const float* __restrict__ x, const unsigned short* __restrict__ Wbf,
    float* __restrict__ wbuf)
{
    __shared__ float sm[4][16][SM_STRIDE];   // 62.5 KB

    const int tid = threadIdx.x;
    const int w   = tid >> 6;          // wave id 0..3 (K-slice)
    const int l   = tid & 63;
    const int m0  = blockIdx.x * 16;
    const int row = l & 15;
    const int kg  = l >> 4;            // 0..3

    f32x4 acc[15];
    #pragma unroll
    for (int nt = 0; nt < 15; ++nt) acc[nt] = (f32x4){0.f, 0.f, 0.f, 0.f};

    const float* xp = x + (size_t)(m0 + row) * C_DIM + w * 256 + kg * 8;
    const unsigned short* wp = Wbf + (size_t)row * C_DIM + w * 256 + kg * 8;

    #pragma unroll 2
    for (int ks = 0; ks < 8; ++ks) {
        const int k = ks * 32;
        // A fragment: 8 consecutive fp32 -> bf16
        float4 a0 = *reinterpret_cast<const float4*>(xp + k);
        float4 a1 = *reinterpret_cast<const float4*>(xp + k + 4);
        bf16x8 af;
        af[0] = (short)f2bf(a0.x); af[1] = (short)f2bf(a0.y);
        af[2] = (short)f2bf(a0.z); af[3] = (short)f2bf(a0.w);
        af[4] = (short)f2bf(a1.x); af[5] = (short)f2bf(a1.y);
        af[6] = (short)f2bf(a1.z); af[7] = (short)f2bf(a1.w);
        // B fragments: 15 x 16B bf16 loads (L2-resident Wbf)
        bf16x8 bfr[15];
        #pragma unroll
        for (int nt = 0; nt < 15; ++nt)
            bfr[nt] = *reinterpret_cast<const bf16x8*>(wp + (size_t)nt * 16 * C_DIM + k);
        #pragma unroll
        for (int nt = 0; nt < 15; ++nt)
            acc[nt] = __builtin_amdgcn_mfma_f32_16x16x32_bf16(af, bfr[nt], acc[nt], 0, 0, 0);
    }

    // scatter partial logits: D row = kg*4+j, col = nt*16 + row
    #pragma unroll
    for (int nt = 0; nt < 15; ++nt)
        #pragma unroll
        for (int j = 0; j < 4; ++j)
            sm[w][kg * 4 + j][nt * 16 + row] = acc[nt][j];
    __syncthreads();

    // reduce 4 K-slices + softmax; thread = one (row r, head h)
    const int r = tid >> 4;            // 0..15
    const int h = tid & 15;            // 0..15
    float s[K_TAPS];
    #pragma unroll
    for (int kk = 0; kk < K_TAPS; ++kk) {
        const int c = h * K_TAPS + kk;
        s[kk] = sm[0][r][c] + sm[1][r][c] + sm[2][r][c] + sm[3][r][c];
    }
    float mx = s[0];
    #pragma unroll
    for (int kk = 1; kk < K_TAPS; ++kk) mx = fmaxf(mx, s[kk]);
    float sum = 0.f;
    #pragma unroll
    for (int kk = 0; kk < K_TAPS; ++kk) {
        s[kk] = __expf(s[kk] - mx);
        sum += s[kk];
    }
    const float inv = 1.f / sum;
    float* dst = wbuf + (size_t)(m0 + r) * N_DIM + h * K_TAPS;
    #pragma unroll
    for (int kk = 0; kk < K_TAPS; ++kk) dst[kk] = s[kk] * inv;
}

// ---------------- Kernel 2: depthwise causal conv along t --------------------
// grid = (T/64, B*H); block 256. Stage x[t0-14 .. t0+63, b, h*64 .. +63] in LDS,
// then each thread keeps its 31 x-values in registers (16 outputs x 15 taps).
__global__ __launch_bounds__(256) void conv_kernel(
    const float* __restrict__ x, const float* __restrict__ wbuf,
    float* __restrict__ out)
{
    __shared__ float xs[64 + K_TAPS - 1][R_DIM];   // 78 x 64 = 20 KB

    const int tid = threadIdx.x;
    const int t0 = blockIdx.x * 64;
    const int bh = blockIdx.y;
    const int b = bh >> 4;          // bh = b*16 + h
    const int h = bh & 15;
    const int cbase = h * R_DIM;

    // stage with float4 (78 rows x 16 quads)
    for (int idx = tid; idx < (64 + K_TAPS - 1) * 16; idx += 256) {
        int rrow = idx >> 4, q = idx & 15;
        int t = t0 - (K_TAPS - 1) + rrow;
        float4 v = (t >= 0)
            ? *reinterpret_cast<const float4*>(x + ((size_t)t * B_DIM + b) * C_DIM + cbase + q * 4)
            : (float4){0.f, 0.f, 0.f, 0.f};
        *reinterpret_cast<float4*>(&xs[rrow][q * 4]) = v;
    }
    __syncthreads();

    const int r = tid & 63;
    const int tg = __builtin_amdgcn_readfirstlane(tid >> 6);   // wave-uniform 0..3

    // 31 x-values in registers: xs[tg*16 + j][r], j = 0..30
    float xv[31];
    #pragma unroll
    for (int j = 0; j < 31; ++j) xv[j] = xs[tg * 16 + j][r];

    float accv[16];
    #pragma unroll
    for (int i = 0; i < 16; ++i) accv[i] = 0.f;

    #pragma unroll
    for (int i = 0; i < 16; ++i) {
        const int t = t0 + tg * 16 + i;                        // wave-uniform
        const float* wv = wbuf + ((size_t)t * B_DIM + b) * N_DIM + h * K_TAPS;
        #pragma unroll
        for (int k = 0; k < K_TAPS; ++k)
            accv[i] += wv[k] * xv[i + k];
    }

    #pragma unroll
    for (int i = 0; i < 16; ++i) {
        const int t = t0 + tg * 16 + i;
        out[((size_t)t * B_DIM + b) * C_DIM + cbase + r] = accv[i];
    }
}

extern "C" void kernel_launch(void* const* d_in, const int* in_sizes, int n_in,
                              void* d_out, int out_size, void* d_ws, size_t ws_size,
                              hipStream_t stream) {
    const float* x    = (const float*)d_in[0];   // (T,B,C) fp32
    const float* Wlin = (const float*)d_in[1];   // (240,1024) fp32
    float* out  = (float*)d_out;                 // (T,B,C) fp32

    // ws layout: [wbuf fp32 8192*240 = 7.86 MB][Wbf bf16 240*1024 = 0.49 MB]
    float* wbuf = (float*)d_ws;
    unsigned short* Wbf = (unsigned short*)((char*)d_ws + (size_t)M_DIM * N_DIM * sizeof(float));

    convert_w<<<(N_DIM * C_DIM) / (256 * 4), 256, 0, stream>>>(Wlin, Wbf);
    gemm_softmax_mfma<<<M_DIM / 16, 256, 0, stream>>>(x, Wbf, wbuf);
    conv_kernel<<<dim3(T_DIM / 64, B_DIM * H_DIM), 256, 0, stream>>>(x, wbuf, out);
}

// Round 6
// 125.135 us; speedup vs baseline: 3.8212x; 1.0219x over previous
//
#include <hip/hip_runtime.h>
#include <hip/hip_bf16.h>

// DynamicConv1dTBC fused: T=2048 B=4 C=1024 H=16 K=15 PAD_L=14 (causal)
// out[t,b,h*64+r] = sum_k softmax_k(x[t,b,:]·Wlin[h*15+k,:]) * x[t+k-14,b,h*64+r]
//
// Single fused kernel per (t-tile=16, b): logits GEMM (split-K over 4 waves,
// bf16 MFMA) -> LDS reduce + softmax -> banded-matrix A-fragments in LDS ->
// conv as MFMA: out(16x16c) = Wband(16x32) @ xT(32x16c), two c-halves.

#define T_DIM 2048
#define B_DIM 4
#define C_DIM 1024
#define H_DIM 16
#define K_TAPS 15
#define N_DIM 240
#define SM_STRIDE 244
#define SM_FLOATS (4 * 16 * SM_STRIDE)   // 15616 floats = 62.46 KB
#define XT_STRIDE 34                     // ushorts per c-row (32 k + 2 pad)
#define XT_OFF 4096                      // float offset of xT region
// LDS unions (all inside smem[SM_FLOATS]):
//   phase1/2: partials [4][16][SM_STRIDE] fp32
//   phase3:   wsA ushort[16 h][64 lane][8]   = floats [0, 4096)
//             xT  ushort[512 c][XT_STRIDE]   = floats [4096, 12800)

typedef __attribute__((ext_vector_type(8))) short bf16x8;
typedef __attribute__((ext_vector_type(4))) float f32x4;

__device__ __forceinline__ unsigned short f2bf(float f) {
    union { float f; unsigned u; } v; v.f = f;
    return (unsigned short)((v.u + 0x7FFFu + ((v.u >> 16) & 1u)) >> 16);
}

// ---------------- Kernel 0: convert Wlin (240x1024 fp32) -> bf16 ------------
__global__ __launch_bounds__(256) void convert_w(
    const float* __restrict__ W, unsigned short* __restrict__ Wbf)
{
    int i = (blockIdx.x * 256 + threadIdx.x) * 4;   // grid covers 245760 elems
    float4 v = *reinterpret_cast<const float4*>(W + i);
    ushort4 o;
    o.x = f2bf(v.x); o.y = f2bf(v.y); o.z = f2bf(v.z); o.w = f2bf(v.w);
    *reinterpret_cast<ushort4*>(Wbf + i) = o;
}

// ---------------- Fused kernel: grid (T/16, B), 256 threads -----------------
__global__ __launch_bounds__(256, 2) void fused_dynconv(
    const float* __restrict__ x, const unsigned short* __restrict__ Wbf,
    float* __restrict__ out)
{
    __shared__ float smem[SM_FLOATS];

    const int tid = threadIdx.x;
    const int wv  = tid >> 6;          // wave id 0..3 (K-slice in phase 1)
    const int l   = tid & 63;
    const int t0  = blockIdx.x * 16;
    const int b   = blockIdx.y;
    const int row = l & 15;
    const int kg  = l >> 4;            // 0..3

    // ===== Phase 1: logits GEMM, M=16 rows (t0..t0+15 at batch b), split-K ==
    const float* xp = x + ((size_t)(t0 + row) * B_DIM + b) * C_DIM + wv * 256 + kg * 8;
    const unsigned short* wp = Wbf + (size_t)row * C_DIM + wv * 256 + kg * 8;

    // issue all 8 K-step x-loads up front (one HBM latency, not eight)
    float4 xa[8], xb[8];
    #pragma unroll
    for (int ks = 0; ks < 8; ++ks) {
        xa[ks] = *reinterpret_cast<const float4*>(xp + ks * 32);
        xb[ks] = *reinterpret_cast<const float4*>(xp + ks * 32 + 4);
    }

    f32x4 acc[15];
    #pragma unroll
    for (int nt = 0; nt < 15; ++nt) acc[nt] = (f32x4){0.f, 0.f, 0.f, 0.f};

    #pragma unroll
    for (int ks = 0; ks < 8; ++ks) {
        bf16x8 bfr[15];
        #pragma unroll
        for (int nt = 0; nt < 15; ++nt)
            bfr[nt] = *reinterpret_cast<const bf16x8*>(wp + (size_t)nt * 16 * C_DIM + ks * 32);
        bf16x8 af;
        af[0] = (short)f2bf(xa[ks].x); af[1] = (short)f2bf(xa[ks].y);
        af[2] = (short)f2bf(xa[ks].z); af[3] = (short)f2bf(xa[ks].w);
        af[4] = (short)f2bf(xb[ks].x); af[5] = (short)f2bf(xb[ks].y);
        af[6] = (short)f2bf(xb[ks].z); af[7] = (short)f2bf(xb[ks].w);
        #pragma unroll
        for (int nt = 0; nt < 15; ++nt)
            acc[nt] = __builtin_amdgcn_mfma_f32_16x16x32_bf16(af, bfr[nt], acc[nt], 0, 0, 0);
    }

    // scatter partials: D lane l reg j -> row (l>>4)*4+j, col l&15 (m89 layout)
    #pragma unroll
    for (int nt = 0; nt < 15; ++nt)
        #pragma unroll
        for (int j = 0; j < 4; ++j)
            smem[(wv * 16 + kg * 4 + j) * SM_STRIDE + nt * 16 + row] = acc[nt][j];
    __syncthreads();                                          // #1

    // ===== Phase 2: reduce 4 K-slices + softmax; thread = (row rr, head hh) =
    const int rr = tid >> 4;
    const int hh = tid & 15;
    float wn[K_TAPS];
    #pragma unroll
    for (int kk = 0; kk < K_TAPS; ++kk) {
        const int c = hh * K_TAPS + kk;
        wn[kk] = smem[(0 * 16 + rr) * SM_STRIDE + c] + smem[(1 * 16 + rr) * SM_STRIDE + c]
               + smem[(2 * 16 + rr) * SM_STRIDE + c] + smem[(3 * 16 + rr) * SM_STRIDE + c];
    }
    float mx = wn[0];
    #pragma unroll
    for (int kk = 1; kk < K_TAPS; ++kk) mx = fmaxf(mx, wn[kk]);
    float sum = 0.f;
    #pragma unroll
    for (int kk = 0; kk < K_TAPS; ++kk) { wn[kk] = __expf(wn[kk] - mx); sum += wn[kk]; }
    const float inv = 1.f / sum;
    __syncthreads();                                          // #2 (all reads done)

    // zero the FULL wsA region: 4096 floats = 16 KB = 256 threads x 4 int4
    unsigned short* wsA = reinterpret_cast<unsigned short*>(smem);
    {
        int4 z = {0, 0, 0, 0};
        int4* p = reinterpret_cast<int4*>(smem) + tid * 4;
        p[0] = z; p[1] = z; p[2] = z; p[3] = z;
    }
    __syncthreads();                                          // #3

    // A[row=rr][k=rr+tap] = wn[tap]; layout wsA[h][g*16+row][j], k = g*8+j
    // (store-side runtime address; source index 'tap' stays compile-time)
    #pragma unroll
    for (int tap = 0; tap < K_TAPS; ++tap) {
        const int k = rr + tap;                               // 0..29 < 32
        wsA[hh * 512 + (k >> 3) * 128 + rr * 8 + (k & 7)] = f2bf(wn[tap] * inv);
    }

    // ===== Phase 3: conv as MFMA over two c-halves =========================
    unsigned short* xT = reinterpret_cast<unsigned short*>(smem + XT_OFF);
    const int c4 = (tid & 127) * 4;     // 0..508
    const int k2 = tid >> 7;            // 0..1
    #pragma unroll 1
    for (int q = 0; q < 2; ++q) {
        // stage x[t0-14+k][q*512 + c] -> xT[c][k] bf16 (k = 0..31, zero-pad OOB)
        #pragma unroll 4
        for (int k = 0; k < 32; k += 2) {
            const int kk = k + k2;
            const int ta = t0 - 14 + kk;
            float4 v = (ta >= 0 && ta < T_DIM)
                ? *reinterpret_cast<const float4*>(x + ((size_t)ta * B_DIM + b) * C_DIM + q * 512 + c4)
                : (float4){0.f, 0.f, 0.f, 0.f};
            xT[(c4 + 0) * XT_STRIDE + kk] = f2bf(v.x);
            xT[(c4 + 1) * XT_STRIDE + kk] = f2bf(v.y);
            xT[(c4 + 2) * XT_STRIDE + kk] = f2bf(v.z);
            xT[(c4 + 3) * XT_STRIDE + kk] = f2bf(v.w);
        }
        __syncthreads();                                      // staging + wsA ready

        // wave wv owns heads h0, h0+1 (4 c-tiles each) in this half
        const int h0 = q * 8 + wv * 2;
        const bf16x8 A0 = *reinterpret_cast<const bf16x8*>(wsA + (h0 * 64 + l) * 8);
        const bf16x8 A1 = *reinterpret_cast<const bf16x8*>(wsA + ((h0 + 1) * 64 + l) * 8);
        const int* xTi = reinterpret_cast<const int*>(xT);
        #pragma unroll
        for (int i = 0; i < 8; ++i) {
            const int ct = q * 32 + wv * 8 + i;               // global c-tile
            const int cl = (wv * 8 + i) * 16 + row;           // local xT row (c)
            const int base = cl * (XT_STRIDE / 2) + kg * 4;   // int-element index
            int4 bi;
            bi.x = xTi[base + 0]; bi.y = xTi[base + 1];
            bi.z = xTi[base + 2]; bi.w = xTi[base + 3];
            union { int4 i4; bf16x8 h; } u; u.i4 = bi;
            f32x4 d = __builtin_amdgcn_mfma_f32_16x16x32_bf16(
                (i < 4) ? A0 : A1, u.h, (f32x4){0.f, 0.f, 0.f, 0.f}, 0, 0, 0);
            #pragma unroll
            for (int j = 0; j < 4; ++j)
                out[((size_t)(t0 + kg * 4 + j) * B_DIM + b) * C_DIM + ct * 16 + row] = d[j];
        }
        __syncthreads();                                      // before restaging xT
    }
}

extern "C" void kernel_launch(void* const* d_in, const int* in_sizes, int n_in,
                              void* d_out, int out_size, void* d_ws, size_t ws_size,
                              hipStream_t stream) {
    const float* x    = (const float*)d_in[0];   // (T,B,C) fp32
    const float* Wlin = (const float*)d_in[1];   // (240,1024) fp32
    float* out = (float*)d_out;                  // (T,B,C) fp32
    unsigned short* Wbf = (unsigned short*)d_ws; // 240*1024 bf16 = 480 KB

    convert_w<<<(N_DIM * C_DIM) / (256 * 4), 256, 0, stream>>>(Wlin, Wbf);
    fused_dynconv<<<dim3(T_DIM / 16, B_DIM), 256, 0, stream>>>(x, Wbf, out);
}